// Round 1
// baseline (480.501 us; speedup 1.0000x reference)
//
#include <hip/hip_runtime.h>
#include <hip/hip_bf16.h>

#define N_TOK 4096
#define DIM   1024
#define NEXP  8
#define FDIM  4096
#define KCAP  512

typedef __attribute__((ext_vector_type(8))) short bf16x8;
typedef __attribute__((ext_vector_type(4))) float floatx4;

__device__ inline unsigned short f2bf(float f) {
  union { float f; unsigned int i; } v; v.f = f;
  unsigned int r = v.i + 0x7fffu + ((v.i >> 16) & 1u);
  return (unsigned short)(r >> 16);
}

// async global->LDS, 16 B per lane; LDS dest = wave-uniform base + lane*16
__device__ inline void ld2lds16(const void* g, void* l) {
  __builtin_amdgcn_global_load_lds(
      (const __attribute__((address_space(1))) unsigned int*)g,
      (__attribute__((address_space(3))) unsigned int*)l,
      16, 0, 0);
}

// ---------------- fused prep: router(+x->bf16) | W1 transpose | W2 transpose
// blocks [0,1024): router, 4 tokens/block, writes probs_t and xb
// blocks [1024,33792): W1 [E][D][F] f32 -> w1t [E][F][D] bf16
// blocks [33792,66560): W2 [E][F][D] f32 -> w2t [E][D][F] bf16
__global__ __launch_bounds__(256)
void prep_kernel(const float* __restrict__ x,
                 const float* __restrict__ Ws,
                 const float* __restrict__ bs,
                 float* __restrict__ probs_t,
                 unsigned short* __restrict__ xb,
                 const float* __restrict__ W1, unsigned short* __restrict__ w1t,
                 const float* __restrict__ W2, unsigned short* __restrict__ w2t) {
  __shared__ unsigned short tile[32][40];
  int bid = blockIdx.x;
  int t = threadIdx.x;

  if (bid >= 1024) {
    // ---- transpose+convert path ----
    const float* src; unsigned short* dst; int R, C, bx, by, bz;
    int b = bid - 1024;
    if (b < 32768) {
      src = W1; dst = w1t; R = DIM; C = FDIM;
      bx = b & 127; by = (b >> 7) & 31; bz = b >> 12;
    } else {
      b -= 32768;
      src = W2; dst = w2t; R = FDIM; C = DIM;
      bx = b & 31; by = (b >> 5) & 127; bz = b >> 12;
    }
    size_t off = (size_t)bz * R * C;
    int r0 = by * 32, c0 = bx * 32;
    int tr = t >> 3, tc = (t & 7) * 4;
    float4 v = *(const float4*)&src[off + (size_t)(r0 + tr) * C + (c0 + tc)];
    tile[tr][tc + 0] = f2bf(v.x);
    tile[tr][tc + 1] = f2bf(v.y);
    tile[tr][tc + 2] = f2bf(v.z);
    tile[tr][tc + 3] = f2bf(v.w);
    __syncthreads();
    ushort4 o;
    o.x = tile[tc + 0][tr];
    o.y = tile[tc + 1][tr];
    o.z = tile[tc + 2][tr];
    o.w = tile[tc + 3][tr];
    *(ushort4*)&dst[off + (size_t)(c0 + tr) * R + (r0 + tc)] = o;
    return;
  }

  // ---- router path (fp64 logits+softmax) + x fp32->bf16 ----
  int token = bid * 4 + (t >> 6);
  int lane  = t & 63;
  const float* xr = x + (size_t)token * DIM;
  unsigned short* xbr = xb + (size_t)token * DIM;
  double acc[NEXP];
#pragma unroll
  for (int e = 0; e < NEXP; e++) acc[e] = 0.0;
#pragma unroll
  for (int c = 0; c < 4; c++) {
    int d0 = (c * 64 + lane) * 4;
    float4 xv = *(const float4*)&xr[d0];
    ushort4 ob;
    ob.x = f2bf(xv.x); ob.y = f2bf(xv.y); ob.z = f2bf(xv.z); ob.w = f2bf(xv.w);
    *(ushort4*)&xbr[d0] = ob;
    float xa[4] = {xv.x, xv.y, xv.z, xv.w};
#pragma unroll
    for (int q = 0; q < 4; q++) {
      const float* wr = &Ws[(size_t)(d0 + q) * NEXP];
      float4 w0 = *(const float4*)&wr[0];
      float4 w1 = *(const float4*)&wr[4];
      double xs = (double)xa[q];
      acc[0] += xs * (double)w0.x; acc[1] += xs * (double)w0.y;
      acc[2] += xs * (double)w0.z; acc[3] += xs * (double)w0.w;
      acc[4] += xs * (double)w1.x; acc[5] += xs * (double)w1.y;
      acc[6] += xs * (double)w1.z; acc[7] += xs * (double)w1.w;
    }
  }
#pragma unroll
  for (int off = 32; off > 0; off >>= 1)
#pragma unroll
    for (int e = 0; e < NEXP; e++) acc[e] += __shfl_down(acc[e], off, 64);
  if (lane == 0) {
    double mx = -1e300;
#pragma unroll
    for (int e = 0; e < NEXP; e++) { acc[e] += (double)bs[e]; if (acc[e] > mx) mx = acc[e]; }
    double s = 0.0, p[NEXP];
#pragma unroll
    for (int e = 0; e < NEXP; e++) { p[e] = exp(acc[e] - mx); s += p[e]; }
#pragma unroll
    for (int e = 0; e < NEXP; e++) probs_t[(size_t)e * N_TOK + token] = (float)(p[e] / s);
  }
}

// ------- top-k per expert: radix-histogram select of 512 from 4096 ---------
// fused: also builds counts[token] and inv[token][..] (old invidx kernel)
__global__ __launch_bounds__(1024)
void topk_kernel(const float* __restrict__ probs_t, int* __restrict__ routes,
                 float* __restrict__ vals, int* __restrict__ counts,
                 int* __restrict__ inv) {
  int e = blockIdx.x;
  const float* P = probs_t + (size_t)e * N_TOK;
  __shared__ int hist[4096];
  __shared__ int hist2[4096];
  __shared__ int scan[1024];
  __shared__ int sB, sR, sCnt;
  __shared__ unsigned int sPrefix, sMask;
  int t = threadIdx.x;

  float vv[4];
  unsigned int vb[4];
  float4 v4 = *(const float4*)&P[t * 4];
  vv[0] = v4.x; vv[1] = v4.y; vv[2] = v4.z; vv[3] = v4.w;
#pragma unroll
  for (int q = 0; q < 4; q++) vb[q] = __float_as_uint(vv[q]);

  if (t == 0) { sR = KCAP; sPrefix = 0u; sMask = 0u; sCnt = 0; }
  __syncthreads();

  for (int level = 0; level < 3; level++) {
    int nb    = (level < 2) ? 4096 : 256;
    int shift = (level == 0) ? 20 : (level == 1) ? 8 : 0;
    for (int i = t; i < nb; i += 1024) hist[i] = 0;
    __syncthreads();
    unsigned int msk = sMask, pfx = sPrefix;
#pragma unroll
    for (int q = 0; q < 4; q++)
      if ((vb[q] & msk) == pfx)
        atomicAdd(&hist[(vb[q] >> shift) & (nb - 1)], 1);
    __syncthreads();
    int* src = hist; int* dst = hist2;
    for (int d = 1; d < nb; d <<= 1) {
      for (int i = t; i < nb; i += 1024)
        dst[i] = src[i] + ((i + d < nb) ? src[i + d] : 0);
      int* tmp = src; src = dst; dst = tmp;
      __syncthreads();
    }
    int R = sR;
    for (int i = t; i < nb; i += 1024) {
      int si = src[i];
      int sn = (i + 1 < nb) ? src[i + 1] : 0;
      if (si >= R && sn < R) sB = i;
    }
    __syncthreads();
    if (t == 0) {
      int B = sB;
      int strict = (B + 1 < nb) ? src[B + 1] : 0;
      sR = sR - strict;
      sPrefix |= ((unsigned int)B) << shift;
      sMask   |= ((unsigned int)(nb - 1)) << shift;
    }
    __syncthreads();
  }

  unsigned int T = sPrefix;
  int R = sR;
  int cnt = 0;
#pragma unroll
  for (int q = 0; q < 4; q++) if (vb[q] == T) cnt++;
  scan[t] = cnt;
  __syncthreads();
  for (int d = 1; d < 1024; d <<= 1) {
    int v = (t >= d) ? scan[t - d] : 0;
    __syncthreads();
    scan[t] += v;
    __syncthreads();
  }
  int grank = scan[t] - cnt;
#pragma unroll
  for (int q = 0; q < 4; q++) {
    bool sel = false;
    if (vb[q] > T) sel = true;
    else if (vb[q] == T) { if (grank < R) sel = true; grank++; }
    if (sel) {
      int pos = atomicAdd(&sCnt, 1);
      int slot = e * KCAP + pos;
      int token = t * 4 + q;
      routes[slot] = token;
      vals[slot]   = vv[q];
      int pc = atomicAdd(&counts[token], 1);
      inv[token * NEXP + pc] = slot;
    }
  }
}

// ---------------- GEMM1: h = gelu(xb[routes] @ W1t^T + b1) ------------------
// LDS: unpadded [128][64] per operand, XOR-chunk swizzle; global_load_lds x16B.
// h layout: [e][fb=f/64][slot][64] so gemm2 A-staging is 1KB-contiguous.
// 1D grid + XCD swizzle: all 128 blocks of expert e land on XCD e.
__global__ __launch_bounds__(256, 3)
void gemm1_kernel(const unsigned short* __restrict__ xb,
                  const unsigned short* __restrict__ w1t,   // [E][F][D] bf16
                  const float* __restrict__ b1,
                  const int* __restrict__ routes,
                  unsigned short* __restrict__ h) {
  int lb = blockIdx.x;                       // 1024 blocks
  int sb = ((lb & 7) << 7) | (lb >> 3);      // bijective XCD swizzle
  int nt = sb & 31, mt = (sb >> 5) & 3, e = sb >> 7;
  __shared__ unsigned short smem[16384];           // As 8192 | Bs 8192 (32 KB)
  unsigned short* As = smem;
  unsigned short* Bs = smem + 8192;
  int t = threadIdx.x, lane = t & 63, wave = t >> 6;
  int wm = (wave >> 1) * 64, wn = (wave & 1) * 64;
  int fr = lane & 15, fq = lane >> 4;
  int lrow = lane >> 3, lchunk = (lane & 7) ^ (lrow & 7);
  int sw = fr & 7;

  const unsigned short* aP[4];
  const unsigned short* bP[4];
#pragma unroll
  for (int q = 0; q < 4; q++) {
    int m = wave * 4 + q;
    int row = m * 8 + lrow;
    int token = routes[e * KCAP + mt * 128 + row];
    aP[q] = xb + (size_t)token * DIM + lchunk * 8;
    bP[q] = w1t + ((size_t)e * FDIM + nt * 128 + row) * DIM + lchunk * 8;
  }

  floatx4 acc[4][4];
#pragma unroll
  for (int i = 0; i < 4; i++)
#pragma unroll
    for (int j = 0; j < 4; j++) acc[i][j] = (floatx4)0.0f;

  for (int k0 = 0; k0 < DIM; k0 += 64) {
    __syncthreads();
#pragma unroll
    for (int q = 0; q < 4; q++) {
      int m = wave * 4 + q;
      ld2lds16(aP[q] + k0, As + m * 512);
      ld2lds16(bP[q] + k0, Bs + m * 512);
    }
    __syncthreads();
#pragma unroll
    for (int ks = 0; ks < 2; ks++) {
      bf16x8 af[4], bf[4];
      int cs = ((ks << 2) | fq) ^ sw;
#pragma unroll
      for (int i = 0; i < 4; i++)
        af[i] = *(const bf16x8*)&As[(wm + i * 16 + fr) * 64 + cs * 8];
#pragma unroll
      for (int j = 0; j < 4; j++)
        bf[j] = *(const bf16x8*)&Bs[(wn + j * 16 + fr) * 64 + cs * 8];
#pragma unroll
      for (int i = 0; i < 4; i++)
#pragma unroll
        for (int j = 0; j < 4; j++)
          acc[i][j] = __builtin_amdgcn_mfma_f32_16x16x32_bf16(af[i], bf[j], acc[i][j], 0, 0, 0);
    }
  }

  // epilogue: gelu -> stage through LDS (two 128x64 f32 passes) -> bf16x8 stores
  float bias[4];
#pragma unroll
  for (int j = 0; j < 4; j++) bias[j] = b1[e * FDIM + nt * 128 + wn + j * 16 + fr];
  float* LC = (float*)smem;                       // [128][64] fp32 = 32 KB
#pragma unroll
  for (int p = 0; p < 2; p++) {
    __syncthreads();
    if ((wn >> 6) == p) {
#pragma unroll
      for (int i = 0; i < 4; i++)
#pragma unroll
        for (int r = 0; r < 4; r++) {
          int lr = wm + i * 16 + fq * 4 + r;
#pragma unroll
          for (int j = 0; j < 4; j++) {
            float v = acc[i][j][r] + bias[j];
            float u = 0.7978845608028654f * (v + 0.044715f * v * v * v);
            LC[lr * 64 + j * 16 + fr] = v * __builtin_amdgcn_rcpf(1.0f + __expf(-2.0f * u));
          }
        }
    }
    __syncthreads();
    int row = t >> 1, ch = (t & 1) * 32;
    size_t hb = (((size_t)e * 64 + nt * 2 + p) * KCAP + mt * 128 + row) * 64 + ch;
    const float* lrow2 = &LC[row * 64 + ch];
#pragma unroll
    for (int qq = 0; qq < 4; qq++) {
      bf16x8 o;
#pragma unroll
      for (int u8 = 0; u8 < 8; u8++) o[u8] = (short)f2bf(lrow2[qq * 8 + u8]);
      *(bf16x8*)&h[hb + qq * 8] = o;
    }
  }
}

// ------- GEMM2 split-K=2: partial[s][slot][d] = vs * (h(half) @ W2t^T (+b2 s==0))
__global__ __launch_bounds__(256, 3)
void gemm2_kernel(const unsigned short* __restrict__ h,    // [e][fb][slot][64]
                  const unsigned short* __restrict__ w2t,  // [E][D][F] bf16
                  const float* __restrict__ b2,
                  const float* __restrict__ vals,
                  float* __restrict__ partials) {          // [2][4096][1024]
  int lb = blockIdx.x;                       // 512 blocks
  int sb = ((lb & 7) << 6) | (lb >> 3);      // bijective XCD swizzle
  int nt = sb & 7, mt = (sb >> 3) & 3, z = sb >> 5;
  int e = z >> 1, s = z & 1;
  __shared__ unsigned short smem[16384];
  unsigned short* As = smem;
  unsigned short* Bs = smem + 8192;
  int t = threadIdx.x, lane = t & 63, wave = t >> 6;
  int wm = (wave >> 1) * 64, wn = (wave & 1) * 64;
  int fr = lane & 15, fq = lane >> 4;
  int lrow = lane >> 3, lchunk = (lane & 7) ^ (lrow & 7);
  int sw = fr & 7;

  const unsigned short* aP[4];
  const unsigned short* bP[4];
#pragma unroll
  for (int q = 0; q < 4; q++) {
    int m = wave * 4 + q;
    int row = m * 8 + lrow;
    aP[q] = h + (((size_t)e * 64 + s * 32) * KCAP + mt * 128 + row) * 64 + lchunk * 8;
    bP[q] = w2t + ((size_t)e * DIM + nt * 128 + row) * FDIM + s * 2048 + lchunk * 8;
  }

  floatx4 acc[4][4];
#pragma unroll
  for (int i = 0; i < 4; i++)
#pragma unroll
    for (int j = 0; j < 4; j++) acc[i][j] = (floatx4)0.0f;

  for (int k0 = 0; k0 < 2048; k0 += 64) {
    __syncthreads();
#pragma unroll
    for (int q = 0; q < 4; q++) {
      int m = wave * 4 + q;
      ld2lds16(aP[q] + (size_t)k0 * 512, As + m * 512);   // next fb stride = 512*64
      ld2lds16(bP[q] + k0, Bs + m * 512);
    }
    __syncthreads();
#pragma unroll
    for (int ks = 0; ks < 2; ks++) {
      bf16x8 af[4], bf[4];
      int cs = ((ks << 2) | fq) ^ sw;
#pragma unroll
      for (int i = 0; i < 4; i++)
        af[i] = *(const bf16x8*)&As[(wm + i * 16 + fr) * 64 + cs * 8];
#pragma unroll
      for (int j = 0; j < 4; j++)
        bf[j] = *(const bf16x8*)&Bs[(wn + j * 16 + fr) * 64 + cs * 8];
#pragma unroll
      for (int i = 0; i < 4; i++)
#pragma unroll
        for (int j = 0; j < 4; j++)
          acc[i][j] = __builtin_amdgcn_mfma_f32_16x16x32_bf16(af[i], bf[j], acc[i][j], 0, 0, 0);
    }
  }

  // epilogue: scale by vals[slot], stage C through LDS for coalesced stores
  float* LC = (float*)smem;                       // [128][64] fp32 = 32 KB
  float* outp = partials + (size_t)s * N_TOK * DIM;
  int slotbase = e * KCAP + mt * 128;
  float bias[4];
#pragma unroll
  for (int j = 0; j < 4; j++)
    bias[j] = (s == 0) ? b2[e * DIM + nt * 128 + wn + j * 16 + fr] : 0.0f;
#pragma unroll
  for (int p = 0; p < 2; p++) {
    __syncthreads();
    if ((wn >> 6) == p) {
#pragma unroll
      for (int i = 0; i < 4; i++)
#pragma unroll
        for (int r = 0; r < 4; r++) {
          int lr = wm + i * 16 + fq * 4 + r;
          float vs = vals[slotbase + lr];
#pragma unroll
          for (int j = 0; j < 4; j++)
            LC[lr * 64 + j * 16 + fr] = (acc[i][j][r] + bias[j]) * vs;
        }
    }
    __syncthreads();
    int row = t >> 1, ch = (t & 1) * 32;
    float* dst = outp + (size_t)(slotbase + row) * DIM + nt * 128 + p * 64 + ch;
#pragma unroll
    for (int qq = 0; qq < 8; qq++)
      *(float4*)&dst[qq * 4] = *(const float4*)&LC[row * 64 + ch + qq * 4];
  }
}

// -------- combine: out[token] = sum_slots sum_s partial[s][slot] (pre-scaled)
__global__ __launch_bounds__(256)
void combine_kernel(const float* __restrict__ partials, const int* __restrict__ counts,
                    const int* __restrict__ inv, float* __restrict__ out) {
  int token = blockIdx.x;
  int t = threadIdx.x;
  int c = counts[token];
  float4 acc = {0.f, 0.f, 0.f, 0.f};
  for (int i = 0; i < c; i++) {
    int slot = inv[token * NEXP + i];
    const float* base = partials + (size_t)slot * DIM + t * 4;
#pragma unroll
    for (int s = 0; s < 2; s++) {
      float4 v = *(const float4*)&base[(size_t)s * N_TOK * DIM];
      acc.x += v.x; acc.y += v.y; acc.z += v.z; acc.w += v.w;
    }
  }
  *(float4*)&out[(size_t)token * DIM + t * 4] = acc;
}

extern "C" void kernel_launch(void* const* d_in, const int* in_sizes, int n_in,
                              void* d_out, int out_size, void* d_ws, size_t ws_size,
                              hipStream_t stream) {
  const float* x  = (const float*)d_in[0];
  const float* Ws = (const float*)d_in[1];
  const float* bs = (const float*)d_in[2];
  const float* W1 = (const float*)d_in[3];
  const float* b1 = (const float*)d_in[4];
  const float* W2 = (const float*)d_in[5];
  const float* b2 = (const float*)d_in[6];
  float* out = (float*)d_out;

  char* ws = (char*)d_ws;
  unsigned short* w1t = (unsigned short*)ws; ws += (size_t)NEXP * FDIM * DIM * 2;  // 67 MB
  unsigned short* w2t = (unsigned short*)ws; ws += (size_t)NEXP * DIM * FDIM * 2;  // 67 MB
  unsigned short* h   = (unsigned short*)ws; ws += (size_t)NEXP * KCAP * FDIM * 2; // 33.5 MB
  // xb (8.4 MB) aliases the partials region (33.6 MB): xb dead before gemm2 writes
  char* pshare = ws; ws += (size_t)2 * N_TOK * DIM * 4;
  unsigned short* xb = (unsigned short*)pshare;
  float* partials    = (float*)pshare;
  float* probs  = (float*)ws; ws += (size_t)NEXP * N_TOK * 4;
  int*   routes = (int*)ws;   ws += NEXP * KCAP * 4;
  float* vals   = (float*)ws; ws += NEXP * KCAP * 4;
  int*   counts = (int*)ws;   ws += N_TOK * 4;
  int*   inv    = (int*)ws;   ws += N_TOK * NEXP * 4;

  hipMemsetAsync(counts, 0, N_TOK * sizeof(int), stream);
  // fused: router(+convx) | transpose W1 | transpose W2
  prep_kernel<<<1024 + 32768 + 32768, 256, 0, stream>>>(x, Ws, bs, probs, xb,
                                                        W1, w1t, W2, w2t);
  topk_kernel<<<NEXP, 1024, 0, stream>>>(probs, routes, vals, counts, inv);
  gemm1_kernel<<<1024, 256, 0, stream>>>(xb, w1t, b1, routes, h);
  gemm2_kernel<<<512, 256, 0, stream>>>(h, w2t, b2, vals, partials);
  combine_kernel<<<N_TOK, 256, 0, stream>>>(partials, counts, inv, out);
}

// Round 2
// 440.688 us; speedup vs baseline: 1.0903x; 1.0903x over previous
//
#include <hip/hip_runtime.h>
#include <hip/hip_bf16.h>

#define N_TOK 4096
#define DIM   1024
#define NEXP  8
#define FDIM  4096
#define KCAP  512

typedef __attribute__((ext_vector_type(8))) short bf16x8;
typedef __attribute__((ext_vector_type(4))) float floatx4;

__device__ inline unsigned short f2bf(float f) {
  union { float f; unsigned int i; } v; v.f = f;
  unsigned int r = v.i + 0x7fffu + ((v.i >> 16) & 1u);
  return (unsigned short)(r >> 16);
}

// async global->LDS, 16 B per lane; LDS dest = wave-uniform base + lane*16
__device__ inline void ld2lds16(const void* g, void* l) {
  __builtin_amdgcn_global_load_lds(
      (const __attribute__((address_space(1))) unsigned int*)g,
      (__attribute__((address_space(3))) unsigned int*)l,
      16, 0, 0);
}

// 64x64 fp32->bf16 transpose tile through padded LDS.
// [64][66] ushort: write side ~2-way (free), read side 4-way; 16B global stores.
__device__ inline void transpose64(const float* __restrict__ src,
                                   unsigned short* __restrict__ dst,
                                   int R, int C, int e, int by, int bx, int t,
                                   unsigned short (*tile)[66]) {
  size_t off = (size_t)e * R * C;
  int r0 = by * 64, c0 = bx * 64;
  const float* S = src + off + (size_t)r0 * C + c0;
#pragma unroll
  for (int p = 0; p < 4; p++) {
    int r = (t >> 4) + p * 16, c = (t & 15) * 4;
    float4 v = *(const float4*)&S[(size_t)r * C + c];
    tile[r][c + 0] = f2bf(v.x);
    tile[r][c + 1] = f2bf(v.y);
    tile[r][c + 2] = f2bf(v.z);
    tile[r][c + 3] = f2bf(v.w);
  }
  __syncthreads();
  unsigned short* D = dst + off + (size_t)c0 * R + r0;
#pragma unroll
  for (int p = 0; p < 2; p++) {
    int oc = (t >> 3) + p * 32;   // src col = dst row
    int orr = (t & 7) * 8;        // src row = dst col
    bf16x8 o;
#pragma unroll
    for (int j = 0; j < 8; j++) o[j] = (short)tile[orr + j][oc];
    *(bf16x8*)&D[(size_t)oc * R + orr] = o;
  }
}

// ---------------- fused prep: router(+x->bf16) | W1 transpose ---------------
// blocks [0,1024): router, 4 tokens/block, writes probs_t and xb
// blocks [1024,9216): W1 [E][D][F] f32 -> wt [E][F][D] bf16 (64x64 tiles)
__global__ __launch_bounds__(256)
void prep_kernel(const float* __restrict__ x,
                 const float* __restrict__ Ws,
                 const float* __restrict__ bs,
                 float* __restrict__ probs_t,
                 unsigned short* __restrict__ xb,
                 const float* __restrict__ W1, unsigned short* __restrict__ wt) {
  __shared__ unsigned short tile[64][66];
  int bid = blockIdx.x;
  int t = threadIdx.x;

  if (bid >= 1024) {
    int b = bid - 1024;
    int e = b >> 10, rem = b & 1023;
    int bx = rem & 63, by = rem >> 6;          // R=DIM rows, C=FDIM cols
    transpose64(W1, wt, DIM, FDIM, e, by, bx, t, tile);
    return;
  }

  // ---- router path (fp64 logits+softmax) + x fp32->bf16 ----
  int token = bid * 4 + (t >> 6);
  int lane  = t & 63;
  const float* xr = x + (size_t)token * DIM;
  unsigned short* xbr = xb + (size_t)token * DIM;
  double acc[NEXP];
#pragma unroll
  for (int e = 0; e < NEXP; e++) acc[e] = 0.0;
#pragma unroll
  for (int c = 0; c < 4; c++) {
    int d0 = (c * 64 + lane) * 4;
    float4 xv = *(const float4*)&xr[d0];
    ushort4 ob;
    ob.x = f2bf(xv.x); ob.y = f2bf(xv.y); ob.z = f2bf(xv.z); ob.w = f2bf(xv.w);
    *(ushort4*)&xbr[d0] = ob;
    float xa[4] = {xv.x, xv.y, xv.z, xv.w};
#pragma unroll
    for (int q = 0; q < 4; q++) {
      const float* wr = &Ws[(size_t)(d0 + q) * NEXP];
      float4 w0 = *(const float4*)&wr[0];
      float4 w1 = *(const float4*)&wr[4];
      double xs = (double)xa[q];
      acc[0] += xs * (double)w0.x; acc[1] += xs * (double)w0.y;
      acc[2] += xs * (double)w0.z; acc[3] += xs * (double)w0.w;
      acc[4] += xs * (double)w1.x; acc[5] += xs * (double)w1.y;
      acc[6] += xs * (double)w1.z; acc[7] += xs * (double)w1.w;
    }
  }
#pragma unroll
  for (int off = 32; off > 0; off >>= 1)
#pragma unroll
    for (int e = 0; e < NEXP; e++) acc[e] += __shfl_down(acc[e], off, 64);
  if (lane == 0) {
    double mx = -1e300;
#pragma unroll
    for (int e = 0; e < NEXP; e++) { acc[e] += (double)bs[e]; if (acc[e] > mx) mx = acc[e]; }
    double s = 0.0, p[NEXP];
#pragma unroll
    for (int e = 0; e < NEXP; e++) { p[e] = exp(acc[e] - mx); s += p[e]; }
#pragma unroll
    for (int e = 0; e < NEXP; e++) probs_t[(size_t)e * N_TOK + token] = (float)(p[e] / s);
  }
}

// ---------------- W2 transpose (runs after gemm1, right before gemm2) -------
// W2 [E][F][D] f32 -> wt [E][D][F] bf16 (64x64 tiles)
__global__ __launch_bounds__(256)
void t2_kernel(const float* __restrict__ W2, unsigned short* __restrict__ wt) {
  __shared__ unsigned short tile[64][66];
  int b = blockIdx.x, t = threadIdx.x;
  int e = b >> 10, rem = b & 1023;
  int bx = rem & 15, by = rem >> 4;            // R=FDIM rows, C=DIM cols
  transpose64(W2, wt, FDIM, DIM, e, by, bx, t, tile);
}

// ------- top-k per expert: radix-histogram select of 512 from 4096 ---------
// fused: also builds counts[token] and inv[token][..]
__global__ __launch_bounds__(1024)
void topk_kernel(const float* __restrict__ probs_t, int* __restrict__ routes,
                 float* __restrict__ vals, int* __restrict__ counts,
                 int* __restrict__ inv) {
  int e = blockIdx.x;
  const float* P = probs_t + (size_t)e * N_TOK;
  __shared__ int hist[4096];
  __shared__ int hist2[4096];
  __shared__ int scan[1024];
  __shared__ int sB, sR, sCnt;
  __shared__ unsigned int sPrefix, sMask;
  int t = threadIdx.x;

  float vv[4];
  unsigned int vb[4];
  float4 v4 = *(const float4*)&P[t * 4];
  vv[0] = v4.x; vv[1] = v4.y; vv[2] = v4.z; vv[3] = v4.w;
#pragma unroll
  for (int q = 0; q < 4; q++) vb[q] = __float_as_uint(vv[q]);

  if (t == 0) { sR = KCAP; sPrefix = 0u; sMask = 0u; sCnt = 0; }
  __syncthreads();

  for (int level = 0; level < 3; level++) {
    int nb    = (level < 2) ? 4096 : 256;
    int shift = (level == 0) ? 20 : (level == 1) ? 8 : 0;
    for (int i = t; i < nb; i += 1024) hist[i] = 0;
    __syncthreads();
    unsigned int msk = sMask, pfx = sPrefix;
#pragma unroll
    for (int q = 0; q < 4; q++)
      if ((vb[q] & msk) == pfx)
        atomicAdd(&hist[(vb[q] >> shift) & (nb - 1)], 1);
    __syncthreads();
    int* src = hist; int* dst = hist2;
    for (int d = 1; d < nb; d <<= 1) {
      for (int i = t; i < nb; i += 1024)
        dst[i] = src[i] + ((i + d < nb) ? src[i + d] : 0);
      int* tmp = src; src = dst; dst = tmp;
      __syncthreads();
    }
    int R = sR;
    for (int i = t; i < nb; i += 1024) {
      int si = src[i];
      int sn = (i + 1 < nb) ? src[i + 1] : 0;
      if (si >= R && sn < R) sB = i;
    }
    __syncthreads();
    if (t == 0) {
      int B = sB;
      int strict = (B + 1 < nb) ? src[B + 1] : 0;
      sR = sR - strict;
      sPrefix |= ((unsigned int)B) << shift;
      sMask   |= ((unsigned int)(nb - 1)) << shift;
    }
    __syncthreads();
  }

  unsigned int T = sPrefix;
  int R = sR;
  int cnt = 0;
#pragma unroll
  for (int q = 0; q < 4; q++) if (vb[q] == T) cnt++;
  scan[t] = cnt;
  __syncthreads();
  for (int d = 1; d < 1024; d <<= 1) {
    int v = (t >= d) ? scan[t - d] : 0;
    __syncthreads();
    scan[t] += v;
    __syncthreads();
  }
  int grank = scan[t] - cnt;
#pragma unroll
  for (int q = 0; q < 4; q++) {
    bool sel = false;
    if (vb[q] > T) sel = true;
    else if (vb[q] == T) { if (grank < R) sel = true; grank++; }
    if (sel) {
      int pos = atomicAdd(&sCnt, 1);
      int slot = e * KCAP + pos;
      int token = t * 4 + q;
      routes[slot] = token;
      vals[slot]   = vv[q];
      int pc = atomicAdd(&counts[token], 1);
      inv[token * NEXP + pc] = slot;
    }
  }
}

// ---------------- GEMM1: h = gelu(xb[routes] @ wt^T + b1) -------------------
__global__ __launch_bounds__(256, 3)
void gemm1_kernel(const unsigned short* __restrict__ xb,
                  const unsigned short* __restrict__ w1t,   // [E][F][D] bf16
                  const float* __restrict__ b1,
                  const int* __restrict__ routes,
                  unsigned short* __restrict__ h) {
  int lb = blockIdx.x;                       // 1024 blocks
  int sb = ((lb & 7) << 7) | (lb >> 3);      // bijective XCD swizzle
  int nt = sb & 31, mt = (sb >> 5) & 3, e = sb >> 7;
  __shared__ unsigned short smem[16384];           // As 8192 | Bs 8192 (32 KB)
  unsigned short* As = smem;
  unsigned short* Bs = smem + 8192;
  int t = threadIdx.x, lane = t & 63, wave = t >> 6;
  int wm = (wave >> 1) * 64, wn = (wave & 1) * 64;
  int fr = lane & 15, fq = lane >> 4;
  int lrow = lane >> 3, lchunk = (lane & 7) ^ (lrow & 7);
  int sw = fr & 7;

  const unsigned short* aP[4];
  const unsigned short* bP[4];
#pragma unroll
  for (int q = 0; q < 4; q++) {
    int m = wave * 4 + q;
    int row = m * 8 + lrow;
    int token = routes[e * KCAP + mt * 128 + row];
    aP[q] = xb + (size_t)token * DIM + lchunk * 8;
    bP[q] = w1t + ((size_t)e * FDIM + nt * 128 + row) * DIM + lchunk * 8;
  }

  floatx4 acc[4][4];
#pragma unroll
  for (int i = 0; i < 4; i++)
#pragma unroll
    for (int j = 0; j < 4; j++) acc[i][j] = (floatx4)0.0f;

  for (int k0 = 0; k0 < DIM; k0 += 64) {
    __syncthreads();
#pragma unroll
    for (int q = 0; q < 4; q++) {
      int m = wave * 4 + q;
      ld2lds16(aP[q] + k0, As + m * 512);
      ld2lds16(bP[q] + k0, Bs + m * 512);
    }
    __syncthreads();
#pragma unroll
    for (int ks = 0; ks < 2; ks++) {
      bf16x8 af[4], bf[4];
      int cs = ((ks << 2) | fq) ^ sw;
#pragma unroll
      for (int i = 0; i < 4; i++)
        af[i] = *(const bf16x8*)&As[(wm + i * 16 + fr) * 64 + cs * 8];
#pragma unroll
      for (int j = 0; j < 4; j++)
        bf[j] = *(const bf16x8*)&Bs[(wn + j * 16 + fr) * 64 + cs * 8];
#pragma unroll
      for (int i = 0; i < 4; i++)
#pragma unroll
        for (int j = 0; j < 4; j++)
          acc[i][j] = __builtin_amdgcn_mfma_f32_16x16x32_bf16(af[i], bf[j], acc[i][j], 0, 0, 0);
    }
  }

  // epilogue: gelu -> stage through LDS (two 128x64 f32 passes) -> bf16x8 stores
  float bias[4];
#pragma unroll
  for (int j = 0; j < 4; j++) bias[j] = b1[e * FDIM + nt * 128 + wn + j * 16 + fr];
  float* LC = (float*)smem;                       // [128][64] fp32 = 32 KB
#pragma unroll
  for (int p = 0; p < 2; p++) {
    __syncthreads();
    if ((wn >> 6) == p) {
#pragma unroll
      for (int i = 0; i < 4; i++)
#pragma unroll
        for (int r = 0; r < 4; r++) {
          int lr = wm + i * 16 + fq * 4 + r;
#pragma unroll
          for (int j = 0; j < 4; j++) {
            float v = acc[i][j][r] + bias[j];
            float u = 0.7978845608028654f * (v + 0.044715f * v * v * v);
            LC[lr * 64 + j * 16 + fr] = v * __builtin_amdgcn_rcpf(1.0f + __expf(-2.0f * u));
          }
        }
    }
    __syncthreads();
    int row = t >> 1, ch = (t & 1) * 32;
    size_t hb = (((size_t)e * 64 + nt * 2 + p) * KCAP + mt * 128 + row) * 64 + ch;
    const float* lrow2 = &LC[row * 64 + ch];
#pragma unroll
    for (int qq = 0; qq < 4; qq++) {
      bf16x8 o;
#pragma unroll
      for (int u8 = 0; u8 < 8; u8++) o[u8] = (short)f2bf(lrow2[qq * 8 + u8]);
      *(bf16x8*)&h[hb + qq * 8] = o;
    }
  }
}

// ------- GEMM2 split-K=2: partial[s][slot][d] = vs * (h(half) @ wt^T (+b2 s==0))
__global__ __launch_bounds__(256, 3)
void gemm2_kernel(const unsigned short* __restrict__ h,    // [e][fb][slot][64]
                  const unsigned short* __restrict__ w2t,  // [E][D][F] bf16
                  const float* __restrict__ b2,
                  const float* __restrict__ vals,
                  float* __restrict__ partials) {          // [2][4096][1024]
  int lb = blockIdx.x;                       // 512 blocks
  int sb = ((lb & 7) << 6) | (lb >> 3);      // bijective XCD swizzle
  int nt = sb & 7, mt = (sb >> 3) & 3, z = sb >> 5;
  int e = z >> 1, s = z & 1;
  __shared__ unsigned short smem[16384];
  unsigned short* As = smem;
  unsigned short* Bs = smem + 8192;
  int t = threadIdx.x, lane = t & 63, wave = t >> 6;
  int wm = (wave >> 1) * 64, wn = (wave & 1) * 64;
  int fr = lane & 15, fq = lane >> 4;
  int lrow = lane >> 3, lchunk = (lane & 7) ^ (lrow & 7);
  int sw = fr & 7;

  const unsigned short* aP[4];
  const unsigned short* bP[4];
#pragma unroll
  for (int q = 0; q < 4; q++) {
    int m = wave * 4 + q;
    int row = m * 8 + lrow;
    aP[q] = h + (((size_t)e * 64 + s * 32) * KCAP + mt * 128 + row) * 64 + lchunk * 8;
    bP[q] = w2t + ((size_t)e * DIM + nt * 128 + row) * FDIM + s * 2048 + lchunk * 8;
  }

  floatx4 acc[4][4];
#pragma unroll
  for (int i = 0; i < 4; i++)
#pragma unroll
    for (int j = 0; j < 4; j++) acc[i][j] = (floatx4)0.0f;

  for (int k0 = 0; k0 < 2048; k0 += 64) {
    __syncthreads();
#pragma unroll
    for (int q = 0; q < 4; q++) {
      int m = wave * 4 + q;
      ld2lds16(aP[q] + (size_t)k0 * 512, As + m * 512);   // next fb stride = 512*64
      ld2lds16(bP[q] + k0, Bs + m * 512);
    }
    __syncthreads();
#pragma unroll
    for (int ks = 0; ks < 2; ks++) {
      bf16x8 af[4], bf[4];
      int cs = ((ks << 2) | fq) ^ sw;
#pragma unroll
      for (int i = 0; i < 4; i++)
        af[i] = *(const bf16x8*)&As[(wm + i * 16 + fr) * 64 + cs * 8];
#pragma unroll
      for (int j = 0; j < 4; j++)
        bf[j] = *(const bf16x8*)&Bs[(wn + j * 16 + fr) * 64 + cs * 8];
#pragma unroll
      for (int i = 0; i < 4; i++)
#pragma unroll
        for (int j = 0; j < 4; j++)
          acc[i][j] = __builtin_amdgcn_mfma_f32_16x16x32_bf16(af[i], bf[j], acc[i][j], 0, 0, 0);
    }
  }

  // epilogue: scale by vals[slot], stage C through LDS for coalesced stores
  float* LC = (float*)smem;                       // [128][64] fp32 = 32 KB
  float* outp = partials + (size_t)s * N_TOK * DIM;
  int slotbase = e * KCAP + mt * 128;
  float bias[4];
#pragma unroll
  for (int j = 0; j < 4; j++)
    bias[j] = (s == 0) ? b2[e * DIM + nt * 128 + wn + j * 16 + fr] : 0.0f;
#pragma unroll
  for (int p = 0; p < 2; p++) {
    __syncthreads();
    if ((wn >> 6) == p) {
#pragma unroll
      for (int i = 0; i < 4; i++)
#pragma unroll
        for (int r = 0; r < 4; r++) {
          int lr = wm + i * 16 + fq * 4 + r;
          float vs = vals[slotbase + lr];
#pragma unroll
          for (int j = 0; j < 4; j++)
            LC[lr * 64 + j * 16 + fr] = (acc[i][j][r] + bias[j]) * vs;
        }
    }
    __syncthreads();
    int row = t >> 1, ch = (t & 1) * 32;
    float* dst = outp + (size_t)(slotbase + row) * DIM + nt * 128 + p * 64 + ch;
#pragma unroll
    for (int qq = 0; qq < 8; qq++)
      *(float4*)&dst[qq * 4] = *(const float4*)&LC[row * 64 + ch + qq * 4];
  }
}

// -------- combine: out[token] = sum_slots sum_s partial[s][slot] (pre-scaled)
__global__ __launch_bounds__(256)
void combine_kernel(const float* __restrict__ partials, const int* __restrict__ counts,
                    const int* __restrict__ inv, float* __restrict__ out) {
  int token = blockIdx.x;
  int t = threadIdx.x;
  int c = counts[token];
  float4 acc = {0.f, 0.f, 0.f, 0.f};
  for (int i = 0; i < c; i++) {
    int slot = inv[token * NEXP + i];
    const float* base = partials + (size_t)slot * DIM + t * 4;
#pragma unroll
    for (int s = 0; s < 2; s++) {
      float4 v = *(const float4*)&base[(size_t)s * N_TOK * DIM];
      acc.x += v.x; acc.y += v.y; acc.z += v.z; acc.w += v.w;
    }
  }
  *(float4*)&out[(size_t)token * DIM + t * 4] = acc;
}

extern "C" void kernel_launch(void* const* d_in, const int* in_sizes, int n_in,
                              void* d_out, int out_size, void* d_ws, size_t ws_size,
                              hipStream_t stream) {
  const float* x  = (const float*)d_in[0];
  const float* Ws = (const float*)d_in[1];
  const float* bs = (const float*)d_in[2];
  const float* W1 = (const float*)d_in[3];
  const float* b1 = (const float*)d_in[4];
  const float* W2 = (const float*)d_in[5];
  const float* b2 = (const float*)d_in[6];
  float* out = (float*)d_out;

  char* ws = (char*)d_ws;
  unsigned short* wt = (unsigned short*)ws; ws += (size_t)NEXP * FDIM * DIM * 2;  // 67 MB shared W1t/W2t
  unsigned short* h  = (unsigned short*)ws; ws += (size_t)NEXP * KCAP * FDIM * 2; // 33.5 MB
  // xb (8.4 MB) aliases the partials region (33.6 MB): xb dead before gemm2 writes
  char* pshare = ws; ws += (size_t)2 * N_TOK * DIM * 4;
  unsigned short* xb = (unsigned short*)pshare;
  float* partials    = (float*)pshare;
  float* probs  = (float*)ws; ws += (size_t)NEXP * N_TOK * 4;
  int*   routes = (int*)ws;   ws += NEXP * KCAP * 4;
  float* vals   = (float*)ws; ws += NEXP * KCAP * 4;
  int*   counts = (int*)ws;   ws += N_TOK * 4;
  int*   inv    = (int*)ws;   ws += N_TOK * NEXP * 4;

  hipMemsetAsync(counts, 0, N_TOK * sizeof(int), stream);
  // fused: router(+convx) | transpose W1 -> wt
  prep_kernel<<<1024 + 8192, 256, 0, stream>>>(x, Ws, bs, probs, xb, W1, wt);
  topk_kernel<<<NEXP, 1024, 0, stream>>>(probs, routes, vals, counts, inv);
  gemm1_kernel<<<1024, 256, 0, stream>>>(xb, wt, b1, routes, h);
  // W2 -> wt right before gemm2 (keeps wt L3-hot for gemm2's panel re-reads)
  t2_kernel<<<8192, 256, 0, stream>>>(W2, wt);
  gemm2_kernel<<<512, 256, 0, stream>>>(h, wt, b2, vals, partials);
  combine_kernel<<<N_TOK, 256, 0, stream>>>(partials, counts, inv, out);
}